// Round 1
// baseline (767.732 us; speedup 1.0000x reference)
//
#include <hip/hip_runtime.h>

#define DIMc 2048
#define NHc 16
#define NKVc 4
#define HDc 128
#define Bc 2
#define Tc 2048
#define Mc (Bc*Tc)              // 4096 rows (B*T)
#define NQKVc (DIMc + 2*NKVc*HDc) // 3072

using f32x4 = __attribute__((ext_vector_type(4))) float;
using bf16x8 = __attribute__((ext_vector_type(8))) short;
using u16x4 = __attribute__((ext_vector_type(4))) unsigned short;
typedef unsigned short u16;

__device__ __forceinline__ float bf2f(u16 u) {
  union { unsigned int i; float f; } v; v.i = ((unsigned int)u) << 16; return v.f;
}
__device__ __forceinline__ u16 f2bf(float f) {
  union { float f; unsigned int i; } v; v.f = f;
  unsigned int r = v.i + 0x7fffu + ((v.i >> 16) & 1u);
  return (u16)(r >> 16);
}
__device__ __forceinline__ void gload_lds16(const u16* g, u16* l) {
  __builtin_amdgcn_global_load_lds((__attribute__((address_space(1))) void*)(g),
                                   (__attribute__((address_space(3))) void*)(l), 16, 0, 0);
}

// ---------------- kernel 1: effective (quantized-mix) weights, fp32 -> bf16 -----------
__global__ __launch_bounds__(256) void prep_weights(
    const float* __restrict__ wq, const float* __restrict__ wk,
    const float* __restrict__ wv, const float* __restrict__ wp,
    const float* __restrict__ sfp,
    u16* __restrict__ Wqkv, u16* __restrict__ Wproj)
{
  int row = blockIdx.x; // 0..5119
  const float* src; u16* dst;
  if (row < DIMc)            { src = wq + (row)       * DIMc; dst = Wqkv + row * DIMc; }
  else if (row < DIMc + 512) { src = wk + (row-DIMc)  * DIMc; dst = Wqkv + row * DIMc; }
  else if (row < DIMc + 1024){ src = wv + (row-DIMc-512)*DIMc; dst = Wqkv + row * DIMc; }
  else                       { src = wp + (row-3072)  * DIMc; dst = Wproj + (row-3072) * DIMc; }
  int tid = threadIdx.x;
  float4 a = *(const float4*)(src + tid*8);
  float4 b = *(const float4*)(src + tid*8 + 4);
  float vals[8] = {a.x,a.y,a.z,a.w,b.x,b.y,b.z,b.w};
  float asum = 0.f;
  #pragma unroll
  for (int i = 0; i < 8; i++) asum += fabsf(vals[i]);
  #pragma unroll
  for (int mk = 1; mk < 64; mk <<= 1) asum += __shfl_xor(asum, mk);
  __shared__ float red[4];
  if ((tid & 63) == 0) red[tid >> 6] = asum;
  __syncthreads();
  float scale = fmaxf((red[0]+red[1]+red[2]+red[3]) * (1.0f/DIMc), 1e-8f);
  float thr = 0.7f * scale;
  float sfv = *sfp;
  u16 o[8];
  #pragma unroll
  for (int i = 0; i < 8; i++) {
    float w = vals[i];
    float wqv = (fabsf(w) > thr) ? (w > 0.f ? scale : -scale) : 0.f;
    o[i] = f2bf(w + sfv * (wqv - w));
  }
  *(u16x4*)(dst + tid*8)     = (u16x4){o[0],o[1],o[2],o[3]};
  *(u16x4*)(dst + tid*8 + 4) = (u16x4){o[4],o[5],o[6],o[7]};
}

// ---------------- kernel 2: cast x to bf16 ----------------
__global__ __launch_bounds__(256) void cast_x(const float* __restrict__ x, u16* __restrict__ xb) {
  int i = (blockIdx.x * 256 + threadIdx.x) * 4;
  float4 v = *(const float4*)(x + i);
  *(u16x4*)(xb + i) = (u16x4){f2bf(v.x), f2bf(v.y), f2bf(v.z), f2bf(v.w)};
}

// ---------------- kernel 3: NT bf16 GEMM, C fp32 (m97 recipe) ----------------
// C[m][n] = sum_k A[m][k]*B[n][k];  128x128 tile, BK=32, 4 waves each 64x64
__global__ __launch_bounds__(256, 2) void gemm_nt(
    const u16* __restrict__ A, const u16* __restrict__ Bw,
    float* __restrict__ C, int M, int N, int K)
{
  __shared__ u16 As[128*32];
  __shared__ u16 Bs[128*32];
  const int tid = threadIdx.x;
  const int wave = tid >> 6, lane = tid & 63;
  const int bm = blockIdx.x * 128, bn = blockIdx.y * 128;

  const int srow = lane >> 2;          // 0..15
  const int skoff = (lane & 3) * 8;    // 0,8,16,24
  const u16* gA0 = A  + (bm + wave*16 + srow) * K + skoff;
  const u16* gA1 = gA0 + 64 * K;
  const u16* gB0 = Bw + (bn + wave*16 + srow) * K + skoff;
  const u16* gB1 = gB0 + 64 * K;
  u16* lA0 = &As[(wave*16) * 32];
  u16* lA1 = &As[(64 + wave*16) * 32];
  u16* lB0 = &Bs[(wave*16) * 32];
  u16* lB1 = &Bs[(64 + wave*16) * 32];

  const int wr = (wave >> 1) * 64, wc = (wave & 1) * 64;
  const int fr = lane & 15, fk = (lane >> 4) * 8;

  f32x4 acc[4][4];
  #pragma unroll
  for (int i = 0; i < 4; i++)
    #pragma unroll
    for (int j = 0; j < 4; j++) acc[i][j] = (f32x4){0.f,0.f,0.f,0.f};

  for (int k0 = 0; k0 < K; k0 += 32) {
    __syncthreads();
    gload_lds16(gA0 + k0, lA0);
    gload_lds16(gA1 + k0, lA1);
    gload_lds16(gB0 + k0, lB0);
    gload_lds16(gB1 + k0, lB1);
    __syncthreads();
    bf16x8 af[4], bfr[4];
    #pragma unroll
    for (int i = 0; i < 4; i++) {
      af[i]  = *(const bf16x8*)&As[(wr + i*16 + fr)*32 + fk];
      bfr[i] = *(const bf16x8*)&Bs[(wc + i*16 + fr)*32 + fk];
    }
    #pragma unroll
    for (int i = 0; i < 4; i++)
      #pragma unroll
      for (int j = 0; j < 4; j++)
        acc[i][j] = __builtin_amdgcn_mfma_f32_16x16x32_bf16(af[i], bfr[j], acc[i][j], 0, 0, 0);
  }
  const int col = lane & 15, rb = (lane >> 4) * 4;
  #pragma unroll
  for (int i = 0; i < 4; i++)
    #pragma unroll
    for (int j = 0; j < 4; j++) {
      int r0 = bm + wr + i*16 + rb;
      int c  = bn + wc + j*16 + col;
      #pragma unroll
      for (int r = 0; r < 4; r++)
        C[(r0 + r) * N + c] = acc[i][j][r];
    }
}

// ---------------- kernel 4: rmsnorm + rope + gain, split qkv to head-major bf16 ----------
// blockIdx.x = m*24 + slot ; slot 0..15 q-head, 16..19 k, 20..23 v
__global__ __launch_bounds__(128) void postproc(
    const float* __restrict__ qkv, const float* __restrict__ qgain,
    u16* __restrict__ qb, u16* __restrict__ kb, u16* __restrict__ vb)
{
  int idx = blockIdx.x;
  int slot = idx % 24;
  int m = idx / 24;
  int b = m / Tc, t = m % Tc;
  int d = threadIdx.x;
  if (slot >= 20) { // v: plain cast
    int kvh = slot - 20;
    float val = qkv[m * NQKVc + 2560 + kvh*HDc + d];
    vb[((b*NKVc + kvh)*Tc + t)*HDc + d] = f2bf(val);
    return;
  }
  __shared__ float xn[HDc];
  __shared__ float red[2];
  bool isq = slot < 16;
  int col = isq ? slot*HDc + d : DIMc + (slot-16)*HDc + d;
  float val = qkv[m * NQKVc + col];
  float ss = val * val;
  #pragma unroll
  for (int mk = 1; mk < 64; mk <<= 1) ss += __shfl_xor(ss, mk);
  if ((d & 63) == 0) red[d >> 6] = ss;
  __syncthreads();
  float tot = red[0] + red[1];
  float rn = rsqrtf(tot * (1.0f/HDc) + 1.1920928955078125e-07f);
  xn[d] = val * rn;
  __syncthreads();
  int j = d & 63;
  // inv_freq[j] = 10000^(-j/64) ; exact ref rope: out1 = x1*c + x2*s ; out2 = -x1*s + x2*c
  float invf = exp2f(-(float)j * 0.207620505930460096f); // log2(10000)/64
  float s, c;
  sincosf((float)t * invf, &s, &c);
  float x1 = xn[j], x2 = xn[j + 64];
  float out = (d < 64) ? (x1*c + x2*s) : (-x1*s + x2*c);
  if (isq) {
    out *= qgain[slot];
    qb[((b*NHc + slot)*Tc + t)*HDc + d] = f2bf(out);
  } else {
    kb[((b*NKVc + (slot-16))*Tc + t)*HDc + d] = f2bf(out);
  }
}

// ---------------- kernel 5: flash attention + v-projection removal ----------------
// grid (T/64, B*NH); block 256 = 4 waves; wave w -> 16 q rows
__global__ __launch_bounds__(256, 2) void attn(
    const u16* __restrict__ qb, const u16* __restrict__ kb,
    const u16* __restrict__ vb, u16* __restrict__ yb)
{
  __shared__ u16 Ks[32*128];
  __shared__ u16 Vt[128*32];
  __shared__ u16 Ps[4][16*32];

  const int tid = threadIdx.x, wave = tid >> 6, lane = tid & 63;
  const int qblk = (int)gridDim.x - 1 - (int)blockIdx.x; // heaviest blocks first
  const int bh = blockIdx.y;           // b*NH + h
  const int b = bh >> 4, h = bh & 15;
  const int kvh = h >> 2;
  const int q0 = qblk * 64;
  const int qw = q0 + wave * 16;

  const u16* Qp = qb + ((b*NHc + h)*Tc + qw) * HDc;
  const u16* Kp = kb + ((b*NKVc + kvh)*Tc) * HDc;
  const u16* Vp = vb + ((b*NKVc + kvh)*Tc) * HDc;

  const int fr = lane & 15, quad = lane >> 4, fk = quad * 8;

  bf16x8 qf[4];
  #pragma unroll
  for (int c = 0; c < 4; c++)
    qf[c] = *(const bf16x8*)(Qp + fr*HDc + c*32 + fk);

  f32x4 Oc[8];
  #pragma unroll
  for (int oc = 0; oc < 8; oc++) Oc[oc] = (f32x4){0.f,0.f,0.f,0.f};
  float m_run[4], l_run[4];
  #pragma unroll
  for (int r = 0; r < 4; r++) { m_run[r] = -1e30f; l_run[r] = 0.f; }

  const float scale = 0.08838834764831845f; // 1/sqrt(128)
  const float LOG2E = 1.4426950408889634f;
  const int ntiles = (q0 + 64) / 32;

  for (int it = 0; it < ntiles; it++) {
    const int kv0 = it * 32;
    __syncthreads();
    // stage K rows (row-major 32x128)
    for (int c = tid; c < 512; c += 256) {
      int krow = c >> 4, d = (c & 15) * 8;
      *(bf16x8*)&Ks[krow*128 + d] = *(const bf16x8*)(Kp + (kv0 + krow)*HDc + d);
    }
    // stage V transposed (Vt[d][key])
    for (int c = tid; c < 512; c += 256) {
      int krow = c >> 4, d = (c & 15) * 8;
      bf16x8 vv = *(const bf16x8*)(Vp + (kv0 + krow)*HDc + d);
      #pragma unroll
      for (int j = 0; j < 8; j++) Vt[(d + j)*32 + krow] = (u16)vv[j];
    }
    __syncthreads();
    // S = Q K^T (16 q rows x 32 keys per wave)
    f32x4 s[2];
    s[0] = (f32x4){0.f,0.f,0.f,0.f}; s[1] = (f32x4){0.f,0.f,0.f,0.f};
    #pragma unroll
    for (int cc = 0; cc < 2; cc++)
      #pragma unroll
      for (int c = 0; c < 4; c++) {
        bf16x8 kf = *(const bf16x8*)&Ks[(cc*16 + fr)*128 + c*32 + fk];
        s[cc] = __builtin_amdgcn_mfma_f32_16x16x32_bf16(qf[c], kf, s[cc], 0, 0, 0);
      }
    // online softmax
    float p[2][4], alpha[4];
    #pragma unroll
    for (int r = 0; r < 4; r++) {
      int qrow = qw + quad*4 + r;
      float s0 = s[0][r] * scale, s1 = s[1][r] * scale;
      if (kv0 + fr      > qrow) s0 = -1e30f;
      if (kv0 + 16 + fr > qrow) s1 = -1e30f;
      p[0][r] = s0; p[1][r] = s1;
      float mx = fmaxf(s0, s1);
      mx = fmaxf(mx, __shfl_xor(mx, 1));
      mx = fmaxf(mx, __shfl_xor(mx, 2));
      mx = fmaxf(mx, __shfl_xor(mx, 4));
      mx = fmaxf(mx, __shfl_xor(mx, 8));
      float mnew = fmaxf(m_run[r], mx);
      alpha[r] = exp2f((m_run[r] - mnew) * LOG2E);
      m_run[r] = mnew;
      float sum = 0.f;
      #pragma unroll
      for (int cc = 0; cc < 2; cc++) {
        float e = exp2f((p[cc][r] - mnew) * LOG2E);
        p[cc][r] = e; sum += e;
      }
      sum += __shfl_xor(sum, 1); sum += __shfl_xor(sum, 2);
      sum += __shfl_xor(sum, 4); sum += __shfl_xor(sum, 8);
      l_run[r] = l_run[r] * alpha[r] + sum;
    }
    #pragma unroll
    for (int oc = 0; oc < 8; oc++)
      #pragma unroll
      for (int r = 0; r < 4; r++) Oc[oc][r] *= alpha[r];
    // P: C-layout -> A-layout via LDS round-trip (per-wave region)
    #pragma unroll
    for (int cc = 0; cc < 2; cc++)
      #pragma unroll
      for (int r = 0; r < 4; r++)
        Ps[wave][(quad*4 + r)*32 + cc*16 + fr] = f2bf(p[cc][r]);
    asm volatile("s_waitcnt lgkmcnt(0)" ::: "memory");
    bf16x8 pf = *(const bf16x8*)&Ps[wave][fr*32 + fk];
    // O += P V
    #pragma unroll
    for (int oc = 0; oc < 8; oc++) {
      bf16x8 vf = *(const bf16x8*)&Vt[(oc*16 + fr)*32 + fk];
      Oc[oc] = __builtin_amdgcn_mfma_f32_16x16x32_bf16(pf, vf, Oc[oc], 0, 0, 0);
    }
  }

  // epilogue: normalize, remove projection onto vn(t), store bf16
  #pragma unroll
  for (int r = 0; r < 4; r++) {
    int qrow = qw + quad*4 + r;
    float linv = 1.0f / l_run[r];
    float vv[8], dot = 0.f, n2 = 0.f;
    #pragma unroll
    for (int oc = 0; oc < 8; oc++) {
      float y = Oc[oc][r] * linv;
      Oc[oc][r] = y;
      float v = bf2f(Vp[qrow*HDc + oc*16 + fr]);
      vv[oc] = v; dot += y * v; n2 += v * v;
    }
    dot += __shfl_xor(dot, 1); dot += __shfl_xor(dot, 2);
    dot += __shfl_xor(dot, 4); dot += __shfl_xor(dot, 8);
    n2  += __shfl_xor(n2, 1);  n2  += __shfl_xor(n2, 2);
    n2  += __shfl_xor(n2, 4);  n2  += __shfl_xor(n2, 8);
    float nn = fmaxf(sqrtf(n2), 1e-12f);
    float coef = dot / (nn * nn);
    u16* yrow = yb + (b*Tc + qrow)*DIMc + h*HDc;
    #pragma unroll
    for (int oc = 0; oc < 8; oc++)
      yrow[oc*16 + fr] = f2bf(Oc[oc][r] - coef * vv[oc]);
  }
}

// ---------------- launcher ----------------
extern "C" void kernel_launch(void* const* d_in, const int* in_sizes, int n_in,
                              void* d_out, int out_size, void* d_ws, size_t ws_size,
                              hipStream_t stream) {
  const float* x  = (const float*)d_in[0];
  const float* sf = (const float*)d_in[1];
  const float* wq = (const float*)d_in[2];
  const float* wk = (const float*)d_in[3];
  const float* wv = (const float*)d_in[4];
  const float* wp = (const float*)d_in[5];
  const float* qg = (const float*)d_in[6];
  float* out = (float*)d_out;

  char* p = (char*)d_ws;
  u16* Wqkv  = (u16*)p; p += (size_t)NQKVc * DIMc * 2;       // 12.6 MB
  u16* Wproj = (u16*)p; p += (size_t)DIMc * DIMc * 2;        //  8.4 MB
  u16* xb    = (u16*)p; p += (size_t)Mc * DIMc * 2;          // 16.8 MB (reused as ybuf)
  float* qkvb = (float*)p; p += (size_t)Mc * NQKVc * 4;      // 50.3 MB
  u16* qbuf  = (u16*)p; p += (size_t)Bc * NHc * Tc * HDc * 2;  // 16.8 MB
  u16* kbuf  = (u16*)p; p += (size_t)Bc * NKVc * Tc * HDc * 2; //  4.2 MB
  u16* vbuf  = (u16*)p; p += (size_t)Bc * NKVc * Tc * HDc * 2; //  4.2 MB
  u16* ybuf  = xb; // xb dead after QKV GEMM; attention writes ybuf afterwards

  prep_weights<<<5120, 256, 0, stream>>>(wq, wk, wv, wp, sf, Wqkv, Wproj);
  cast_x<<<(Mc * DIMc) / (256 * 4), 256, 0, stream>>>(x, xb);
  gemm_nt<<<dim3(Mc/128, NQKVc/128), 256, 0, stream>>>(xb, Wqkv, qkvb, Mc, NQKVc, DIMc);
  postproc<<<Mc * 24, 128, 0, stream>>>(qkvb, qg, qbuf, kbuf, vbuf);
  attn<<<dim3(Tc/64, Bc*NHc), 256, 0, stream>>>(qbuf, kbuf, vbuf, ybuf);
  gemm_nt<<<dim3(Mc/128, DIMc/128), 256, 0, stream>>>(ybuf, Wproj, out, Mc, DIMc, DIMc);
}

// Round 2
// 608.846 us; speedup vs baseline: 1.2610x; 1.2610x over previous
//
#include <hip/hip_runtime.h>

#define DIMc 2048
#define NHc 16
#define NKVc 4
#define HDc 128
#define Bc 2
#define Tc 2048
#define Mc (Bc*Tc)              // 4096 rows (B*T)
#define NQKVc (DIMc + 2*NKVc*HDc) // 3072
#define TPc 2080                // padded row stride for V^T (breaks 4KB set aliasing)

using f32x4 = __attribute__((ext_vector_type(4))) float;
using bf16x8 = __attribute__((ext_vector_type(8))) short;
using u16x4 = __attribute__((ext_vector_type(4))) unsigned short;
typedef unsigned short u16;

__device__ __forceinline__ float bf2f(u16 u) {
  union { unsigned int i; float f; } v; v.i = ((unsigned int)u) << 16; return v.f;
}
__device__ __forceinline__ u16 f2bf(float f) {
  union { float f; unsigned int i; } v; v.f = f;
  unsigned int r = v.i + 0x7fffu + ((v.i >> 16) & 1u);
  return (u16)(r >> 16);
}
__device__ __forceinline__ void gload_lds16(const u16* g, u16* l) {
  __builtin_amdgcn_global_load_lds((__attribute__((address_space(1))) void*)(g),
                                   (__attribute__((address_space(3))) void*)(l), 16, 0, 0);
}

// ---------------- kernel 1: effective (quantized-mix) weights, fp32 -> bf16 -----------
__global__ __launch_bounds__(256) void prep_weights(
    const float* __restrict__ wq, const float* __restrict__ wk,
    const float* __restrict__ wv, const float* __restrict__ wp,
    const float* __restrict__ sfp,
    u16* __restrict__ Wqkv, u16* __restrict__ Wproj)
{
  int row = blockIdx.x; // 0..5119
  const float* src; u16* dst;
  if (row < DIMc)            { src = wq + (row)       * DIMc; dst = Wqkv + row * DIMc; }
  else if (row < DIMc + 512) { src = wk + (row-DIMc)  * DIMc; dst = Wqkv + row * DIMc; }
  else if (row < DIMc + 1024){ src = wv + (row-DIMc-512)*DIMc; dst = Wqkv + row * DIMc; }
  else                       { src = wp + (row-3072)  * DIMc; dst = Wproj + (row-3072) * DIMc; }
  int tid = threadIdx.x;
  float4 a = *(const float4*)(src + tid*8);
  float4 b = *(const float4*)(src + tid*8 + 4);
  float vals[8] = {a.x,a.y,a.z,a.w,b.x,b.y,b.z,b.w};
  float asum = 0.f;
  #pragma unroll
  for (int i = 0; i < 8; i++) asum += fabsf(vals[i]);
  #pragma unroll
  for (int mk = 1; mk < 64; mk <<= 1) asum += __shfl_xor(asum, mk);
  __shared__ float red[4];
  if ((tid & 63) == 0) red[tid >> 6] = asum;
  __syncthreads();
  float scale = fmaxf((red[0]+red[1]+red[2]+red[3]) * (1.0f/DIMc), 1e-8f);
  float thr = 0.7f * scale;
  float sfv = *sfp;
  u16 o[8];
  #pragma unroll
  for (int i = 0; i < 8; i++) {
    float w = vals[i];
    float wqv = (fabsf(w) > thr) ? (w > 0.f ? scale : -scale) : 0.f;
    o[i] = f2bf(w + sfv * (wqv - w));
  }
  *(u16x4*)(dst + tid*8)     = (u16x4){o[0],o[1],o[2],o[3]};
  *(u16x4*)(dst + tid*8 + 4) = (u16x4){o[4],o[5],o[6],o[7]};
}

// ---------------- kernel 2: cast x to bf16 ----------------
__global__ __launch_bounds__(256) void cast_x(const float* __restrict__ x, u16* __restrict__ xb) {
  int i = (blockIdx.x * 256 + threadIdx.x) * 4;
  float4 v = *(const float4*)(x + i);
  *(u16x4*)(xb + i) = (u16x4){f2bf(v.x), f2bf(v.y), f2bf(v.z), f2bf(v.w)};
}

// ---------------- kernel 3: NT bf16 GEMM, C fp32 (m97 recipe) ----------------
__global__ __launch_bounds__(256, 2) void gemm_nt(
    const u16* __restrict__ A, const u16* __restrict__ Bw,
    float* __restrict__ C, int M, int N, int K)
{
  __shared__ u16 As[128*32];
  __shared__ u16 Bs[128*32];
  const int tid = threadIdx.x;
  const int wave = tid >> 6, lane = tid & 63;
  const int bm = blockIdx.x * 128, bn = blockIdx.y * 128;

  const int srow = lane >> 2;          // 0..15
  const int skoff = (lane & 3) * 8;    // 0,8,16,24
  const u16* gA0 = A  + (bm + wave*16 + srow) * K + skoff;
  const u16* gA1 = gA0 + 64 * K;
  const u16* gB0 = Bw + (bn + wave*16 + srow) * K + skoff;
  const u16* gB1 = gB0 + 64 * K;
  u16* lA0 = &As[(wave*16) * 32];
  u16* lA1 = &As[(64 + wave*16) * 32];
  u16* lB0 = &Bs[(wave*16) * 32];
  u16* lB1 = &Bs[(64 + wave*16) * 32];

  const int wr = (wave >> 1) * 64, wc = (wave & 1) * 64;
  const int fr = lane & 15, fk = (lane >> 4) * 8;

  f32x4 acc[4][4];
  #pragma unroll
  for (int i = 0; i < 4; i++)
    #pragma unroll
    for (int j = 0; j < 4; j++) acc[i][j] = (f32x4){0.f,0.f,0.f,0.f};

  for (int k0 = 0; k0 < K; k0 += 32) {
    __syncthreads();
    gload_lds16(gA0 + k0, lA0);
    gload_lds16(gA1 + k0, lA1);
    gload_lds16(gB0 + k0, lB0);
    gload_lds16(gB1 + k0, lB1);
    __syncthreads();
    bf16x8 af[4], bfr[4];
    #pragma unroll
    for (int i = 0; i < 4; i++) {
      af[i]  = *(const bf16x8*)&As[(wr + i*16 + fr)*32 + fk];
      bfr[i] = *(const bf16x8*)&Bs[(wc + i*16 + fr)*32 + fk];
    }
    #pragma unroll
    for (int i = 0; i < 4; i++)
      #pragma unroll
      for (int j = 0; j < 4; j++)
        acc[i][j] = __builtin_amdgcn_mfma_f32_16x16x32_bf16(af[i], bfr[j], acc[i][j], 0, 0, 0);
  }
  const int col = lane & 15, rb = (lane >> 4) * 4;
  #pragma unroll
  for (int i = 0; i < 4; i++)
    #pragma unroll
    for (int j = 0; j < 4; j++) {
      int r0 = bm + wr + i*16 + rb;
      int c  = bn + wc + j*16 + col;
      #pragma unroll
      for (int r = 0; r < 4; r++)
        C[(r0 + r) * N + c] = acc[i][j][r];
    }
}

// ---------------- kernel 4: rmsnorm + rope + gain, split qkv to head-major bf16 ----------
__global__ __launch_bounds__(128) void postproc(
    const float* __restrict__ qkv, const float* __restrict__ qgain,
    u16* __restrict__ qb, u16* __restrict__ kb, u16* __restrict__ vb)
{
  int idx = blockIdx.x;
  int slot = idx % 24;
  int m = idx / 24;
  int b = m / Tc, t = m % Tc;
  int d = threadIdx.x;
  if (slot >= 20) { // v: plain cast
    int kvh = slot - 20;
    float val = qkv[m * NQKVc + 2560 + kvh*HDc + d];
    vb[((b*NKVc + kvh)*Tc + t)*HDc + d] = f2bf(val);
    return;
  }
  __shared__ float xn[HDc];
  __shared__ float red[2];
  bool isq = slot < 16;
  int col = isq ? slot*HDc + d : DIMc + (slot-16)*HDc + d;
  float val = qkv[m * NQKVc + col];
  float ss = val * val;
  #pragma unroll
  for (int mk = 1; mk < 64; mk <<= 1) ss += __shfl_xor(ss, mk);
  if ((d & 63) == 0) red[d >> 6] = ss;
  __syncthreads();
  float tot = red[0] + red[1];
  float rn = rsqrtf(tot * (1.0f/HDc) + 1.1920928955078125e-07f);
  xn[d] = val * rn;
  __syncthreads();
  int j = d & 63;
  float invf = exp2f(-(float)j * 0.207620505930460096f); // log2(10000)/64
  float s, c;
  sincosf((float)t * invf, &s, &c);
  float x1 = xn[j], x2 = xn[j + 64];
  float out = (d < 64) ? (x1*c + x2*s) : (-x1*s + x2*c);
  if (isq) {
    out *= qgain[slot];
    qb[((b*NHc + slot)*Tc + t)*HDc + d] = f2bf(out);
  } else {
    kb[((b*NKVc + (slot-16))*Tc + t)*HDc + d] = f2bf(out);
  }
}

// ---------------- kernel 4b: V transpose to [d][t] with padded stride ----------------
// grid (T/64, HD/64, B*NKV); block 256
__global__ __launch_bounds__(256) void transpose_v(
    const u16* __restrict__ vbi, u16* __restrict__ vtb)
{
  __shared__ u16 tile[64][72];
  int t0 = blockIdx.x * 64, d0 = blockIdx.y * 64, s = blockIdx.z;
  const u16* src = vbi + (size_t)s * Tc * HDc;
  u16* dst = vtb + (size_t)s * HDc * TPc;
  int tr = threadIdx.x >> 3;       // 0..31
  int c8 = (threadIdx.x & 7) * 8;  // 0..56
  #pragma unroll
  for (int i = 0; i < 2; i++) {
    int t = i*32 + tr;
    *(bf16x8*)&tile[t][c8] = *(const bf16x8*)(src + (size_t)(t0 + t)*HDc + d0 + c8);
  }
  __syncthreads();
  #pragma unroll
  for (int i = 0; i < 2; i++) {
    int d = i*32 + tr;
    u16 o[8];
    #pragma unroll
    for (int j = 0; j < 8; j++) o[j] = tile[c8 + j][d];
    *(u16x4*)(dst + (size_t)(d0 + d)*TPc + t0 + c8)     = (u16x4){o[0],o[1],o[2],o[3]};
    *(u16x4*)(dst + (size_t)(d0 + d)*TPc + t0 + c8 + 4) = (u16x4){o[4],o[5],o[6],o[7]};
  }
}

// ---------------- kernel 5: flash attention, barrier-free, global-direct K/V^T --------
// grid (T/64, B*NH); block 256 = 4 waves; wave w -> 16 q rows; KV tile = 64
__global__ __launch_bounds__(256) void attn(
    const u16* __restrict__ qb, const u16* __restrict__ kb,
    const u16* __restrict__ vtb, const u16* __restrict__ vb,
    u16* __restrict__ yb)
{
  __shared__ float Ps[4][16*68];   // per-wave P round-trip, fp32, stride 68 (2-way max)

  const int tid = threadIdx.x, wave = tid >> 6, lane = tid & 63;
  const int qblk = (int)gridDim.x - 1 - (int)blockIdx.x; // heaviest first
  const int bh = blockIdx.y;
  const int b = bh >> 4, h = bh & 15;
  const int kvh = h >> 2;
  const int q0 = qblk * 64;
  const int qw = q0 + wave * 16;
  const int fr = lane & 15, quad = lane >> 4;

  const u16* Qp = qb + ((size_t)(b*NHc + h)*Tc + qw) * HDc;
  const u16* Kp = kb + (size_t)(b*NKVc + kvh)*Tc*HDc;
  const u16* Vp = vb + (size_t)(b*NKVc + kvh)*Tc*HDc;
  const u16* Vt = vtb + (size_t)(b*NKVc + kvh)*HDc*TPc;

  bf16x8 qf[4];
  #pragma unroll
  for (int c = 0; c < 4; c++)
    qf[c] = *(const bf16x8*)(Qp + fr*HDc + c*32 + quad*8);

  f32x4 Oc[8];
  #pragma unroll
  for (int oc = 0; oc < 8; oc++) Oc[oc] = (f32x4){0.f,0.f,0.f,0.f};
  float m_run[4], l_run[4];
  #pragma unroll
  for (int r = 0; r < 4; r++) { m_run[r] = -1e30f; l_run[r] = 0.f; }

  const float scale = 0.08838834764831845f; // 1/sqrt(128)
  const float LOG2E = 1.4426950408889634f;
  const int ntiles = q0/64 + 1;

  for (int it = 0; it < ntiles; it++) {
    const int kv0 = it * 64;
    // S = Q K^T : 16 q-rows x 64 keys per wave
    f32x4 s[4];
    #pragma unroll
    for (int cc = 0; cc < 4; cc++) s[cc] = (f32x4){0.f,0.f,0.f,0.f};
    #pragma unroll
    for (int cc = 0; cc < 4; cc++) {
      const u16* kp = Kp + (size_t)(kv0 + cc*16 + fr)*HDc + quad*8;
      bf16x8 kf0 = *(const bf16x8*)(kp);
      bf16x8 kf1 = *(const bf16x8*)(kp + 32);
      bf16x8 kf2 = *(const bf16x8*)(kp + 64);
      bf16x8 kf3 = *(const bf16x8*)(kp + 96);
      s[cc] = __builtin_amdgcn_mfma_f32_16x16x32_bf16(qf[0], kf0, s[cc], 0, 0, 0);
      s[cc] = __builtin_amdgcn_mfma_f32_16x16x32_bf16(qf[1], kf1, s[cc], 0, 0, 0);
      s[cc] = __builtin_amdgcn_mfma_f32_16x16x32_bf16(qf[2], kf2, s[cc], 0, 0, 0);
      s[cc] = __builtin_amdgcn_mfma_f32_16x16x32_bf16(qf[3], kf3, s[cc], 0, 0, 0);
    }
    const bool diag = (it == ntiles - 1);
    // online softmax over 64 keys
    float p[4][4], alpha[4];
    #pragma unroll
    for (int r = 0; r < 4; r++) {
      int qrow = qw + quad*4 + r;
      float mx = -1e30f;
      #pragma unroll
      for (int cc = 0; cc < 4; cc++) {
        float sv = s[cc][r] * scale;
        if (diag && (kv0 + cc*16 + fr > qrow)) sv = -1e30f;
        p[cc][r] = sv;
        mx = fmaxf(mx, sv);
      }
      mx = fmaxf(mx, __shfl_xor(mx, 1));
      mx = fmaxf(mx, __shfl_xor(mx, 2));
      mx = fmaxf(mx, __shfl_xor(mx, 4));
      mx = fmaxf(mx, __shfl_xor(mx, 8));
      float mnew = fmaxf(m_run[r], mx);
      alpha[r] = exp2f((m_run[r] - mnew) * LOG2E);
      m_run[r] = mnew;
      float sum = 0.f;
      #pragma unroll
      for (int cc = 0; cc < 4; cc++) {
        float e = exp2f((p[cc][r] - mnew) * LOG2E);
        p[cc][r] = e; sum += e;
      }
      sum += __shfl_xor(sum, 1); sum += __shfl_xor(sum, 2);
      sum += __shfl_xor(sum, 4); sum += __shfl_xor(sum, 8);
      l_run[r] = l_run[r] * alpha[r] + sum;
    }
    #pragma unroll
    for (int oc = 0; oc < 8; oc++)
      #pragma unroll
      for (int r = 0; r < 4; r++) Oc[oc][r] *= alpha[r];
    // P: C-layout -> A-layout via per-wave LDS (fp32, padded) — no barrier needed
    #pragma unroll
    for (int cc = 0; cc < 4; cc++)
      #pragma unroll
      for (int r = 0; r < 4; r++)
        Ps[wave][(quad*4 + r)*68 + cc*16 + fr] = p[cc][r];
    asm volatile("s_waitcnt lgkmcnt(0)" ::: "memory");
    bf16x8 pf[2];
    #pragma unroll
    for (int kc = 0; kc < 2; kc++) {
      f32x4 a = *(const f32x4*)&Ps[wave][fr*68 + kc*32 + quad*8];
      f32x4 b2 = *(const f32x4*)&Ps[wave][fr*68 + kc*32 + quad*8 + 4];
      pf[kc] = (bf16x8){(short)f2bf(a[0]), (short)f2bf(a[1]), (short)f2bf(a[2]), (short)f2bf(a[3]),
                        (short)f2bf(b2[0]), (short)f2bf(b2[1]), (short)f2bf(b2[2]), (short)f2bf(b2[3])};
    }
    // O += P V  (V^T rows direct from global)
    #pragma unroll
    for (int oc = 0; oc < 8; oc++) {
      const u16* vp = Vt + (size_t)(oc*16 + fr)*TPc + kv0 + quad*8;
      bf16x8 vf0 = *(const bf16x8*)(vp);
      bf16x8 vf1 = *(const bf16x8*)(vp + 32);
      Oc[oc] = __builtin_amdgcn_mfma_f32_16x16x32_bf16(pf[0], vf0, Oc[oc], 0, 0, 0);
      Oc[oc] = __builtin_amdgcn_mfma_f32_16x16x32_bf16(pf[1], vf1, Oc[oc], 0, 0, 0);
    }
  }

  // epilogue: normalize, remove projection onto vn(t), store bf16
  #pragma unroll
  for (int r = 0; r < 4; r++) {
    int qrow = qw + quad*4 + r;
    float linv = 1.0f / l_run[r];
    float vv[8], dot = 0.f, n2 = 0.f;
    #pragma unroll
    for (int oc = 0; oc < 8; oc++) {
      float y = Oc[oc][r] * linv;
      Oc[oc][r] = y;
      float v = bf2f(Vp[(size_t)qrow*HDc + oc*16 + fr]);
      vv[oc] = v; dot += y * v; n2 += v * v;
    }
    dot += __shfl_xor(dot, 1); dot += __shfl_xor(dot, 2);
    dot += __shfl_xor(dot, 4); dot += __shfl_xor(dot, 8);
    n2  += __shfl_xor(n2, 1);  n2  += __shfl_xor(n2, 2);
    n2  += __shfl_xor(n2, 4);  n2  += __shfl_xor(n2, 8);
    float nn = fmaxf(sqrtf(n2), 1e-12f);
    float coef = dot / (nn * nn);
    u16* yrow = yb + ((size_t)(b*Tc) + qrow)*DIMc + h*HDc;
    #pragma unroll
    for (int oc = 0; oc < 8; oc++)
      yrow[oc*16 + fr] = f2bf(Oc[oc][r] - coef * vv[oc]);
  }
}

// ---------------- launcher ----------------
extern "C" void kernel_launch(void* const* d_in, const int* in_sizes, int n_in,
                              void* d_out, int out_size, void* d_ws, size_t ws_size,
                              hipStream_t stream) {
  const float* x  = (const float*)d_in[0];
  const float* sf = (const float*)d_in[1];
  const float* wq = (const float*)d_in[2];
  const float* wk = (const float*)d_in[3];
  const float* wv = (const float*)d_in[4];
  const float* wp = (const float*)d_in[5];
  const float* qg = (const float*)d_in[6];
  float* out = (float*)d_out;

  char* p = (char*)d_ws;
  u16* Wqkv  = (u16*)p; p += (size_t)NQKVc * DIMc * 2;
  u16* Wproj = (u16*)p; p += (size_t)DIMc * DIMc * 2;
  u16* xb    = (u16*)p; p += (size_t)Mc * DIMc * 2;
  float* qkvb = (float*)p; p += (size_t)Mc * NQKVc * 4;
  u16* qbuf  = (u16*)p; p += (size_t)Bc * NHc * Tc * HDc * 2;
  u16* kbuf  = (u16*)p; p += (size_t)Bc * NKVc * Tc * HDc * 2;
  u16* vbuf  = (u16*)p; p += (size_t)Bc * NKVc * Tc * HDc * 2;
  u16* vtbuf = (u16*)p; p += (size_t)Bc * NKVc * HDc * TPc * 2;
  u16* ybuf  = xb; // xb dead after QKV GEMM

  prep_weights<<<5120, 256, 0, stream>>>(wq, wk, wv, wp, sf, Wqkv, Wproj);
  cast_x<<<(Mc * DIMc) / (256 * 4), 256, 0, stream>>>(x, xb);
  gemm_nt<<<dim3(Mc/128, NQKVc/128), 256, 0, stream>>>(xb, Wqkv, qkvb, Mc, NQKVc, DIMc);
  postproc<<<Mc * 24, 128, 0, stream>>>(qkvb, qg, qbuf, kbuf, vbuf);
  transpose_v<<<dim3(Tc/64, HDc/64, Bc*NKVc), 256, 0, stream>>>(vbuf, vtbuf);
  attn<<<dim3(Tc/64, Bc*NHc), 256, 0, stream>>>(qbuf, kbuf, vtbuf, vbuf, ybuf);
  gemm_nt<<<dim3(Mc/128, DIMc/128), 256, 0, stream>>>(ybuf, Wproj, out, Mc, DIMc, DIMc);
}

// Round 3
// 477.795 us; speedup vs baseline: 1.6068x; 1.2743x over previous
//
#include <hip/hip_runtime.h>

#define DIMc 2048
#define NHc 16
#define NKVc 4
#define HDc 128
#define Bc 2
#define Tc 2048
#define Mc (Bc*Tc)              // 4096 rows (B*T)
#define NQKVc (DIMc + 2*NKVc*HDc) // 3072
#define TPc 2080                // padded row stride for V^T (breaks 4KB set aliasing)

using f32x4 = __attribute__((ext_vector_type(4))) float;
using bf16x8 = __attribute__((ext_vector_type(8))) short;
using u16x4 = __attribute__((ext_vector_type(4))) unsigned short;
typedef unsigned short u16;

__device__ __forceinline__ float bf2f(u16 u) {
  union { unsigned int i; float f; } v; v.i = ((unsigned int)u) << 16; return v.f;
}
__device__ __forceinline__ u16 f2bf(float f) {
  union { float f; unsigned int i; } v; v.f = f;
  unsigned int r = v.i + 0x7fffu + ((v.i >> 16) & 1u);
  return (u16)(r >> 16);
}
__device__ __forceinline__ void gload_lds16(const u16* g, u16* l) {
  __builtin_amdgcn_global_load_lds((__attribute__((address_space(1))) void*)(g),
                                   (__attribute__((address_space(3))) void*)(l), 16, 0, 0);
}

// ---------------- kernel 1: effective (quantized-mix) weights, fp32 -> bf16 -----------
__global__ __launch_bounds__(256) void prep_weights(
    const float* __restrict__ wq, const float* __restrict__ wk,
    const float* __restrict__ wv, const float* __restrict__ wp,
    const float* __restrict__ sfp,
    u16* __restrict__ Wqkv, u16* __restrict__ Wproj)
{
  int row = blockIdx.x; // 0..5119
  const float* src; u16* dst;
  if (row < DIMc)            { src = wq + (row)       * DIMc; dst = Wqkv + row * DIMc; }
  else if (row < DIMc + 512) { src = wk + (row-DIMc)  * DIMc; dst = Wqkv + row * DIMc; }
  else if (row < DIMc + 1024){ src = wv + (row-DIMc-512)*DIMc; dst = Wqkv + row * DIMc; }
  else                       { src = wp + (row-3072)  * DIMc; dst = Wproj + (row-3072) * DIMc; }
  int tid = threadIdx.x;
  float4 a = *(const float4*)(src + tid*8);
  float4 b = *(const float4*)(src + tid*8 + 4);
  float vals[8] = {a.x,a.y,a.z,a.w,b.x,b.y,b.z,b.w};
  float asum = 0.f;
  #pragma unroll
  for (int i = 0; i < 8; i++) asum += fabsf(vals[i]);
  #pragma unroll
  for (int mk = 1; mk < 64; mk <<= 1) asum += __shfl_xor(asum, mk);
  __shared__ float red[4];
  if ((tid & 63) == 0) red[tid >> 6] = asum;
  __syncthreads();
  float scale = fmaxf((red[0]+red[1]+red[2]+red[3]) * (1.0f/DIMc), 1e-8f);
  float thr = 0.7f * scale;
  float sfv = *sfp;
  u16 o[8];
  #pragma unroll
  for (int i = 0; i < 8; i++) {
    float w = vals[i];
    float wqv = (fabsf(w) > thr) ? (w > 0.f ? scale : -scale) : 0.f;
    o[i] = f2bf(w + sfv * (wqv - w));
  }
  *(u16x4*)(dst + tid*8)     = (u16x4){o[0],o[1],o[2],o[3]};
  *(u16x4*)(dst + tid*8 + 4) = (u16x4){o[4],o[5],o[6],o[7]};
}

// ---------------- kernel 2: cast x to bf16 ----------------
__global__ __launch_bounds__(256) void cast_x(const float* __restrict__ x, u16* __restrict__ xb) {
  int i = (blockIdx.x * 256 + threadIdx.x) * 4;
  float4 v = *(const float4*)(x + i);
  *(u16x4*)(xb + i) = (u16x4){f2bf(v.x), f2bf(v.y), f2bf(v.z), f2bf(v.w)};
}

// ---------------- kernel 2b: rope cos/sin table ----------------
__global__ __launch_bounds__(256) void rope_table(float* __restrict__ rt) {
  int idx = blockIdx.x * 256 + threadIdx.x;   // t*64 + j, 131072 total
  int t = idx >> 6, j = idx & 63;
  float invf = exp2f(-(float)j * 0.207620505930460096f); // log2(10000)/64
  float s, c;
  sincosf((float)t * invf, &s, &c);
  rt[idx*2]   = c;
  rt[idx*2+1] = s;
}

// ---------------- kernel 3: NT bf16 GEMM, C fp32 (m97 recipe) ----------------
__global__ __launch_bounds__(256, 2) void gemm_nt(
    const u16* __restrict__ A, const u16* __restrict__ Bw,
    float* __restrict__ C, int M, int N, int K)
{
  __shared__ u16 As[128*32];
  __shared__ u16 Bs[128*32];
  const int tid = threadIdx.x;
  const int wave = tid >> 6, lane = tid & 63;
  const int bm = blockIdx.x * 128, bn = blockIdx.y * 128;

  const int srow = lane >> 2;          // 0..15
  const int skoff = (lane & 3) * 8;    // 0,8,16,24
  const u16* gA0 = A  + (bm + wave*16 + srow) * K + skoff;
  const u16* gA1 = gA0 + 64 * K;
  const u16* gB0 = Bw + (bn + wave*16 + srow) * K + skoff;
  const u16* gB1 = gB0 + 64 * K;
  u16* lA0 = &As[(wave*16) * 32];
  u16* lA1 = &As[(64 + wave*16) * 32];
  u16* lB0 = &Bs[(wave*16) * 32];
  u16* lB1 = &Bs[(64 + wave*16) * 32];

  const int wr = (wave >> 1) * 64, wc = (wave & 1) * 64;
  const int fr = lane & 15, fk = (lane >> 4) * 8;

  f32x4 acc[4][4];
  #pragma unroll
  for (int i = 0; i < 4; i++)
    #pragma unroll
    for (int j = 0; j < 4; j++) acc[i][j] = (f32x4){0.f,0.f,0.f,0.f};

  for (int k0 = 0; k0 < K; k0 += 32) {
    __syncthreads();
    gload_lds16(gA0 + k0, lA0);
    gload_lds16(gA1 + k0, lA1);
    gload_lds16(gB0 + k0, lB0);
    gload_lds16(gB1 + k0, lB1);
    __syncthreads();
    bf16x8 af[4], bfr[4];
    #pragma unroll
    for (int i = 0; i < 4; i++) {
      af[i]  = *(const bf16x8*)&As[(wr + i*16 + fr)*32 + fk];
      bfr[i] = *(const bf16x8*)&Bs[(wc + i*16 + fr)*32 + fk];
    }
    #pragma unroll
    for (int i = 0; i < 4; i++)
      #pragma unroll
      for (int j = 0; j < 4; j++)
        acc[i][j] = __builtin_amdgcn_mfma_f32_16x16x32_bf16(af[i], bfr[j], acc[i][j], 0, 0, 0);
  }
  const int col = lane & 15, rb = (lane >> 4) * 4;
  #pragma unroll
  for (int i = 0; i < 4; i++)
    #pragma unroll
    for (int j = 0; j < 4; j++) {
      int r0 = bm + wr + i*16 + rb;
      int c  = bn + wc + j*16 + col;
      #pragma unroll
      for (int r = 0; r < 4; r++)
        C[(r0 + r) * N + c] = acc[i][j][r];
    }
}

// ---------------- kernel 4: rmsnorm + rope(table) + gain, split qkv head-major bf16 ---
__global__ __launch_bounds__(128) void postproc(
    const float* __restrict__ qkv, const float* __restrict__ qgain,
    const float* __restrict__ rt,
    u16* __restrict__ qb, u16* __restrict__ kb, u16* __restrict__ vb)
{
  int idx = blockIdx.x;
  int slot = idx % 24;
  int m = idx / 24;
  int b = m / Tc, t = m % Tc;
  int d = threadIdx.x;
  if (slot >= 20) { // v: plain cast
    int kvh = slot - 20;
    float val = qkv[m * NQKVc + 2560 + kvh*HDc + d];
    vb[((b*NKVc + kvh)*Tc + t)*HDc + d] = f2bf(val);
    return;
  }
  __shared__ float xn[HDc];
  __shared__ float red[2];
  bool isq = slot < 16;
  int col = isq ? slot*HDc + d : DIMc + (slot-16)*HDc + d;
  float val = qkv[m * NQKVc + col];
  float ss = val * val;
  #pragma unroll
  for (int mk = 1; mk < 64; mk <<= 1) ss += __shfl_xor(ss, mk);
  if ((d & 63) == 0) red[d >> 6] = ss;
  __syncthreads();
  float tot = red[0] + red[1];
  float rn = rsqrtf(tot * (1.0f/HDc) + 1.1920928955078125e-07f);
  xn[d] = val * rn;
  __syncthreads();
  int j = d & 63;
  float2 cs = *(const float2*)(rt + (t*64 + j)*2);
  float x1 = xn[j], x2 = xn[j + 64];
  float out = (d < 64) ? (x1*cs.x + x2*cs.y) : (-x1*cs.y + x2*cs.x);
  if (isq) {
    out *= qgain[slot];
    qb[((b*NHc + slot)*Tc + t)*HDc + d] = f2bf(out);
  } else {
    kb[((b*NKVc + (slot-16))*Tc + t)*HDc + d] = f2bf(out);
  }
}

// ---------------- kernel 4b: V transpose to [d][t] with padded stride ----------------
__global__ __launch_bounds__(256) void transpose_v(
    const u16* __restrict__ vbi, u16* __restrict__ vtb)
{
  __shared__ u16 tile[64][72];
  int t0 = blockIdx.x * 64, d0 = blockIdx.y * 64, s = blockIdx.z;
  const u16* src = vbi + (size_t)s * Tc * HDc;
  u16* dst = vtb + (size_t)s * HDc * TPc;
  int tr = threadIdx.x >> 3;       // 0..31
  int c8 = (threadIdx.x & 7) * 8;  // 0..56
  #pragma unroll
  for (int i = 0; i < 2; i++) {
    int t = i*32 + tr;
    *(bf16x8*)&tile[t][c8] = *(const bf16x8*)(src + (size_t)(t0 + t)*HDc + d0 + c8);
  }
  __syncthreads();
  #pragma unroll
  for (int i = 0; i < 2; i++) {
    int d = i*32 + tr;
    u16 o[8];
    #pragma unroll
    for (int j = 0; j < 8; j++) o[j] = tile[c8 + j][d];
    *(u16x4*)(dst + (size_t)(d0 + d)*TPc + t0 + c8)     = (u16x4){o[0],o[1],o[2],o[3]};
    *(u16x4*)(dst + (size_t)(d0 + d)*TPc + t0 + c8 + 4) = (u16x4){o[4],o[5],o[6],o[7]};
  }
}

// ---------------- kernel 5: flash attention, pair-balanced causal, 2 frag streams -----
// grid (16, B*NH); block 256 = 4 waves. Block p handles q-tiles {31-p (frag0), p (frag1)}
// interleaved in one KV sweep: frag0 active all iters, frag1 active while it <= p.
__global__ __launch_bounds__(256, 2) void attn(
    const u16* __restrict__ qb, const u16* __restrict__ kb,
    const u16* __restrict__ vtb, const u16* __restrict__ vb,
    u16* __restrict__ yb)
{
  __shared__ float Ps[4][2][16*68];   // per-wave, per-frag P round-trip (fp32, padded)

  const int tid = threadIdx.x, wave = tid >> 6, lane = tid & 63;
  const int p = blockIdx.x;            // pair index 0..15
  const int bh = blockIdx.y;
  const int b = bh >> 4, h = bh & 15;
  const int kvh = h >> 2;
  const int fr = lane & 15, quad = lane >> 4;

  const int qt0 = 31 - p, qt1 = p;
  const int qw0 = qt0*64 + wave*16, qw1 = qt1*64 + wave*16;

  const u16* Qb = qb + (size_t)(b*NHc + h)*Tc*HDc;
  const u16* Kp = kb + (size_t)(b*NKVc + kvh)*Tc*HDc;
  const u16* Vp = vb + (size_t)(b*NKVc + kvh)*Tc*HDc;
  const u16* Vt = vtb + (size_t)(b*NKVc + kvh)*HDc*TPc;

  bf16x8 qf[2][4];
  #pragma unroll
  for (int c = 0; c < 4; c++) {
    qf[0][c] = *(const bf16x8*)(Qb + (size_t)(qw0 + fr)*HDc + c*32 + quad*8);
    qf[1][c] = *(const bf16x8*)(Qb + (size_t)(qw1 + fr)*HDc + c*32 + quad*8);
  }

  f32x4 Oc[2][8];
  float m_run[2][4], l_run[2][4];
  #pragma unroll
  for (int f = 0; f < 2; f++) {
    #pragma unroll
    for (int oc = 0; oc < 8; oc++) Oc[f][oc] = (f32x4){0.f,0.f,0.f,0.f};
    #pragma unroll
    for (int r = 0; r < 4; r++) { m_run[f][r] = -1e30f; l_run[f][r] = 0.f; }
  }

  const float scale = 0.08838834764831845f; // 1/sqrt(128)
  const float LOG2E = 1.4426950408889634f;
  const int ntiles = 32 - p;

  for (int it = 0; it < ntiles; it++) {
    const int kv0 = it * 64;
    const bool act1 = (it <= p);
    // S = Q K^T for both fragments, shared K loads
    f32x4 s[2][4];
    #pragma unroll
    for (int cc = 0; cc < 4; cc++) { s[0][cc] = (f32x4){0.f,0.f,0.f,0.f}; s[1][cc] = (f32x4){0.f,0.f,0.f,0.f}; }
    #pragma unroll
    for (int cc = 0; cc < 4; cc++) {
      const u16* kp = Kp + (size_t)(kv0 + cc*16 + fr)*HDc + quad*8;
      bf16x8 kf0 = *(const bf16x8*)(kp);
      bf16x8 kf1 = *(const bf16x8*)(kp + 32);
      bf16x8 kf2 = *(const bf16x8*)(kp + 64);
      bf16x8 kf3 = *(const bf16x8*)(kp + 96);
      s[0][cc] = __builtin_amdgcn_mfma_f32_16x16x32_bf16(qf[0][0], kf0, s[0][cc], 0, 0, 0);
      s[0][cc] = __builtin_amdgcn_mfma_f32_16x16x32_bf16(qf[0][1], kf1, s[0][cc], 0, 0, 0);
      s[0][cc] = __builtin_amdgcn_mfma_f32_16x16x32_bf16(qf[0][2], kf2, s[0][cc], 0, 0, 0);
      s[0][cc] = __builtin_amdgcn_mfma_f32_16x16x32_bf16(qf[0][3], kf3, s[0][cc], 0, 0, 0);
      if (act1) {
        s[1][cc] = __builtin_amdgcn_mfma_f32_16x16x32_bf16(qf[1][0], kf0, s[1][cc], 0, 0, 0);
        s[1][cc] = __builtin_amdgcn_mfma_f32_16x16x32_bf16(qf[1][1], kf1, s[1][cc], 0, 0, 0);
        s[1][cc] = __builtin_amdgcn_mfma_f32_16x16x32_bf16(qf[1][2], kf2, s[1][cc], 0, 0, 0);
        s[1][cc] = __builtin_amdgcn_mfma_f32_16x16x32_bf16(qf[1][3], kf3, s[1][cc], 0, 0, 0);
      }
    }
    // online softmax per fragment
    #pragma unroll
    for (int f = 0; f < 2; f++) {
      if (f == 0 || act1) {
        const int qtf = (f == 0) ? qt0 : qt1;
        const int qwf = (f == 0) ? qw0 : qw1;
        const bool diag = (it == qtf);
        #pragma unroll
        for (int r = 0; r < 4; r++) {
          int qrow = qwf + quad*4 + r;
          float pv[4];
          float mx = -1e30f;
          #pragma unroll
          for (int cc = 0; cc < 4; cc++) {
            float sv = s[f][cc][r] * scale;
            if (diag && (kv0 + cc*16 + fr > qrow)) sv = -1e30f;
            pv[cc] = sv;
            mx = fmaxf(mx, sv);
          }
          mx = fmaxf(mx, __shfl_xor(mx, 1));
          mx = fmaxf(mx, __shfl_xor(mx, 2));
          mx = fmaxf(mx, __shfl_xor(mx, 4));
          mx = fmaxf(mx, __shfl_xor(mx, 8));
          float mnew = fmaxf(m_run[f][r], mx);
          float al = exp2f((m_run[f][r] - mnew) * LOG2E);
          m_run[f][r] = mnew;
          float sum = 0.f;
          #pragma unroll
          for (int cc = 0; cc < 4; cc++) {
            float e = exp2f((pv[cc] - mnew) * LOG2E);
            pv[cc] = e; sum += e;
          }
          sum += __shfl_xor(sum, 1); sum += __shfl_xor(sum, 2);
          sum += __shfl_xor(sum, 4); sum += __shfl_xor(sum, 8);
          l_run[f][r] = l_run[f][r] * al + sum;
          #pragma unroll
          for (int oc = 0; oc < 8; oc++) Oc[f][oc][r] *= al;
          #pragma unroll
          for (int cc = 0; cc < 4; cc++)
            Ps[wave][f][(quad*4 + r)*68 + cc*16 + fr] = pv[cc];
        }
      }
    }
    asm volatile("s_waitcnt lgkmcnt(0)" ::: "memory");
    bf16x8 pf[2][2];
    #pragma unroll
    for (int f = 0; f < 2; f++) {
      if (f == 0 || act1) {
        #pragma unroll
        for (int kc = 0; kc < 2; kc++) {
          f32x4 a  = *(const f32x4*)&Ps[wave][f][fr*68 + kc*32 + quad*8];
          f32x4 b2 = *(const f32x4*)&Ps[wave][f][fr*68 + kc*32 + quad*8 + 4];
          pf[f][kc] = (bf16x8){(short)f2bf(a[0]), (short)f2bf(a[1]), (short)f2bf(a[2]), (short)f2bf(a[3]),
                               (short)f2bf(b2[0]), (short)f2bf(b2[1]), (short)f2bf(b2[2]), (short)f2bf(b2[3])};
        }
      }
    }
    // O += P V  (shared V^T loads)
    #pragma unroll
    for (int oc = 0; oc < 8; oc++) {
      const u16* vp = Vt + (size_t)(oc*16 + fr)*TPc + kv0 + quad*8;
      bf16x8 vf0 = *(const bf16x8*)(vp);
      bf16x8 vf1 = *(const bf16x8*)(vp + 32);
      Oc[0][oc] = __builtin_amdgcn_mfma_f32_16x16x32_bf16(pf[0][0], vf0, Oc[0][oc], 0, 0, 0);
      Oc[0][oc] = __builtin_amdgcn_mfma_f32_16x16x32_bf16(pf[0][1], vf1, Oc[0][oc], 0, 0, 0);
      if (act1) {
        Oc[1][oc] = __builtin_amdgcn_mfma_f32_16x16x32_bf16(pf[1][0], vf0, Oc[1][oc], 0, 0, 0);
        Oc[1][oc] = __builtin_amdgcn_mfma_f32_16x16x32_bf16(pf[1][1], vf1, Oc[1][oc], 0, 0, 0);
      }
    }
  }

  // epilogue both fragments: normalize, remove projection onto vn(t), store bf16
  #pragma unroll
  for (int f = 0; f < 2; f++) {
    const int qwf = (f == 0) ? qw0 : qw1;
    #pragma unroll
    for (int r = 0; r < 4; r++) {
      int qrow = qwf + quad*4 + r;
      float linv = 1.0f / l_run[f][r];
      float vv[8], dot = 0.f, n2 = 0.f;
      #pragma unroll
      for (int oc = 0; oc < 8; oc++) {
        float y = Oc[f][oc][r] * linv;
        Oc[f][oc][r] = y;
        float v = bf2f(Vp[(size_t)qrow*HDc + oc*16 + fr]);
        vv[oc] = v; dot += y * v; n2 += v * v;
      }
      dot += __shfl_xor(dot, 1); dot += __shfl_xor(dot, 2);
      dot += __shfl_xor(dot, 4); dot += __shfl_xor(dot, 8);
      n2  += __shfl_xor(n2, 1);  n2  += __shfl_xor(n2, 2);
      n2  += __shfl_xor(n2, 4);  n2  += __shfl_xor(n2, 8);
      float nn = fmaxf(sqrtf(n2), 1e-12f);
      float coef = dot / (nn * nn);
      u16* yrow = yb + ((size_t)(b*Tc) + qrow)*DIMc + h*HDc;
      #pragma unroll
      for (int oc = 0; oc < 8; oc++)
        yrow[oc*16 + fr] = f2bf(Oc[f][oc][r] - coef * vv[oc]);
    }
  }
}

// ---------------- launcher ----------------
extern "C" void kernel_launch(void* const* d_in, const int* in_sizes, int n_in,
                              void* d_out, int out_size, void* d_ws, size_t ws_size,
                              hipStream_t stream) {
  const float* x  = (const float*)d_in[0];
  const float* sf = (const float*)d_in[1];
  const float* wq = (const float*)d_in[2];
  const float* wk = (const float*)d_in[3];
  const float* wv = (const float*)d_in[4];
  const float* wp = (const float*)d_in[5];
  const float* qg = (const float*)d_in[6];
  float* out = (float*)d_out;

  char* p = (char*)d_ws;
  u16* Wqkv  = (u16*)p; p += (size_t)NQKVc * DIMc * 2;
  u16* Wproj = (u16*)p; p += (size_t)DIMc * DIMc * 2;
  u16* xb    = (u16*)p; p += (size_t)Mc * DIMc * 2;
  float* qkvb = (float*)p; p += (size_t)Mc * NQKVc * 4;
  u16* qbuf  = (u16*)p; p += (size_t)Bc * NHc * Tc * HDc * 2;
  u16* kbuf  = (u16*)p; p += (size_t)Bc * NKVc * Tc * HDc * 2;
  u16* vbuf  = (u16*)p; p += (size_t)Bc * NKVc * Tc * HDc * 2;
  u16* vtbuf = (u16*)p; p += (size_t)Bc * NKVc * HDc * TPc * 2;
  float* rtab = (float*)p; p += (size_t)Tc * 64 * 2 * 4;
  u16* ybuf  = xb; // xb dead after QKV GEMM

  prep_weights<<<5120, 256, 0, stream>>>(wq, wk, wv, wp, sf, Wqkv, Wproj);
  cast_x<<<(Mc * DIMc) / (256 * 4), 256, 0, stream>>>(x, xb);
  rope_table<<<(Tc * 64) / 256, 256, 0, stream>>>(rtab);
  gemm_nt<<<dim3(Mc/128, NQKVc/128), 256, 0, stream>>>(xb, Wqkv, qkvb, Mc, NQKVc, DIMc);
  postproc<<<Mc * 24, 128, 0, stream>>>(qkvb, qg, rtab, qbuf, kbuf, vbuf);
  transpose_v<<<dim3(Tc/64, HDc/64, Bc*NKVc), 256, 0, stream>>>(vbuf, vtbuf);
  attn<<<dim3(16, Bc*NHc), 256, 0, stream>>>(qbuf, kbuf, vtbuf, vbuf, ybuf);
  gemm_nt<<<dim3(Mc/128, DIMc/128), 256, 0, stream>>>(ybuf, Wproj, out, Mc, DIMc, DIMc);
}

// Round 4
// 453.687 us; speedup vs baseline: 1.6922x; 1.0531x over previous
//
#include <hip/hip_runtime.h>

#define DIMc 2048
#define NHc 16
#define NKVc 4
#define HDc 128
#define Bc 2
#define Tc 2048
#define Mc (Bc*Tc)              // 4096 rows (B*T)
#define NQKVc (DIMc + 2*NKVc*HDc) // 3072
#define TPc 2080                // padded row stride for V^T (breaks 4KB set aliasing)

using f32x4 = __attribute__((ext_vector_type(4))) float;
using bf16x8 = __attribute__((ext_vector_type(8))) short;
using u16x4 = __attribute__((ext_vector_type(4))) unsigned short;
typedef unsigned short u16;

__device__ __forceinline__ float bf2f(u16 u) {
  union { unsigned int i; float f; } v; v.i = ((unsigned int)u) << 16; return v.f;
}
__device__ __forceinline__ u16 f2bf(float f) {
  union { float f; unsigned int i; } v; v.f = f;
  unsigned int r = v.i + 0x7fffu + ((v.i >> 16) & 1u);
  return (u16)(r >> 16);
}
__device__ __forceinline__ void gload_lds16(const u16* g, u16* l) {
  __builtin_amdgcn_global_load_lds((__attribute__((address_space(1))) void*)(g),
                                   (__attribute__((address_space(3))) void*)(l), 16, 0, 0);
}

// ---------------- kernel 1: effective (quantized-mix) weights, fp32 -> bf16 -----------
__global__ __launch_bounds__(256) void prep_weights(
    const float* __restrict__ wq, const float* __restrict__ wk,
    const float* __restrict__ wv, const float* __restrict__ wp,
    const float* __restrict__ sfp,
    u16* __restrict__ Wqkv, u16* __restrict__ Wproj)
{
  int row = blockIdx.x; // 0..5119
  const float* src; u16* dst;
  if (row < DIMc)            { src = wq + (row)       * DIMc; dst = Wqkv + row * DIMc; }
  else if (row < DIMc + 512) { src = wk + (row-DIMc)  * DIMc; dst = Wqkv + row * DIMc; }
  else if (row < DIMc + 1024){ src = wv + (row-DIMc-512)*DIMc; dst = Wqkv + row * DIMc; }
  else                       { src = wp + (row-3072)  * DIMc; dst = Wproj + (row-3072) * DIMc; }
  int tid = threadIdx.x;
  float4 a = *(const float4*)(src + tid*8);
  float4 b = *(const float4*)(src + tid*8 + 4);
  float vals[8] = {a.x,a.y,a.z,a.w,b.x,b.y,b.z,b.w};
  float asum = 0.f;
  #pragma unroll
  for (int i = 0; i < 8; i++) asum += fabsf(vals[i]);
  #pragma unroll
  for (int mk = 1; mk < 64; mk <<= 1) asum += __shfl_xor(asum, mk);
  __shared__ float red[4];
  if ((tid & 63) == 0) red[tid >> 6] = asum;
  __syncthreads();
  float scale = fmaxf((red[0]+red[1]+red[2]+red[3]) * (1.0f/DIMc), 1e-8f);
  float thr = 0.7f * scale;
  float sfv = *sfp;
  u16 o[8];
  #pragma unroll
  for (int i = 0; i < 8; i++) {
    float w = vals[i];
    float wqv = (fabsf(w) > thr) ? (w > 0.f ? scale : -scale) : 0.f;
    o[i] = f2bf(w + sfv * (wqv - w));
  }
  *(u16x4*)(dst + tid*8)     = (u16x4){o[0],o[1],o[2],o[3]};
  *(u16x4*)(dst + tid*8 + 4) = (u16x4){o[4],o[5],o[6],o[7]};
}

// ---------------- kernel 2: cast x to bf16 ----------------
__global__ __launch_bounds__(256) void cast_x(const float* __restrict__ x, u16* __restrict__ xb) {
  int i = (blockIdx.x * 256 + threadIdx.x) * 4;
  float4 v = *(const float4*)(x + i);
  *(u16x4*)(xb + i) = (u16x4){f2bf(v.x), f2bf(v.y), f2bf(v.z), f2bf(v.w)};
}

// ---------------- kernel 2b: rope cos/sin table ----------------
__global__ __launch_bounds__(256) void rope_table(float* __restrict__ rt) {
  int idx = blockIdx.x * 256 + threadIdx.x;   // t*64 + j, 131072 total
  int t = idx >> 6, j = idx & 63;
  float invf = exp2f(-(float)j * 0.207620505930460096f); // log2(10000)/64
  float s, c;
  sincosf((float)t * invf, &s, &c);
  rt[idx*2]   = c;
  rt[idx*2+1] = s;
}

// ---------------- kernel 3: NT bf16 GEMM, C fp32 (m97 recipe) ----------------
__global__ __launch_bounds__(256, 2) void gemm_nt(
    const u16* __restrict__ A, const u16* __restrict__ Bw,
    float* __restrict__ C, int M, int N, int K)
{
  __shared__ u16 As[128*32];
  __shared__ u16 Bs[128*32];
  const int tid = threadIdx.x;
  const int wave = tid >> 6, lane = tid & 63;
  const int bm = blockIdx.x * 128, bn = blockIdx.y * 128;

  const int srow = lane >> 2;          // 0..15
  const int skoff = (lane & 3) * 8;    // 0,8,16,24
  const u16* gA0 = A  + (bm + wave*16 + srow) * K + skoff;
  const u16* gA1 = gA0 + 64 * K;
  const u16* gB0 = Bw + (bn + wave*16 + srow) * K + skoff;
  const u16* gB1 = gB0 + 64 * K;
  u16* lA0 = &As[(wave*16) * 32];
  u16* lA1 = &As[(64 + wave*16) * 32];
  u16* lB0 = &Bs[(wave*16) * 32];
  u16* lB1 = &Bs[(64 + wave*16) * 32];

  const int wr = (wave >> 1) * 64, wc = (wave & 1) * 64;
  const int fr = lane & 15, fk = (lane >> 4) * 8;

  f32x4 acc[4][4];
  #pragma unroll
  for (int i = 0; i < 4; i++)
    #pragma unroll
    for (int j = 0; j < 4; j++) acc[i][j] = (f32x4){0.f,0.f,0.f,0.f};

  for (int k0 = 0; k0 < K; k0 += 32) {
    __syncthreads();
    gload_lds16(gA0 + k0, lA0);
    gload_lds16(gA1 + k0, lA1);
    gload_lds16(gB0 + k0, lB0);
    gload_lds16(gB1 + k0, lB1);
    __syncthreads();
    bf16x8 af[4], bfr[4];
    #pragma unroll
    for (int i = 0; i < 4; i++) {
      af[i]  = *(const bf16x8*)&As[(wr + i*16 + fr)*32 + fk];
      bfr[i] = *(const bf16x8*)&Bs[(wc + i*16 + fr)*32 + fk];
    }
    #pragma unroll
    for (int i = 0; i < 4; i++)
      #pragma unroll
      for (int j = 0; j < 4; j++)
        acc[i][j] = __builtin_amdgcn_mfma_f32_16x16x32_bf16(af[i], bfr[j], acc[i][j], 0, 0, 0);
  }
  const int col = lane & 15, rb = (lane >> 4) * 4;
  #pragma unroll
  for (int i = 0; i < 4; i++)
    #pragma unroll
    for (int j = 0; j < 4; j++) {
      int r0 = bm + wr + i*16 + rb;
      int c  = bn + wc + j*16 + col;
      #pragma unroll
      for (int r = 0; r < 4; r++)
        C[(r0 + r) * N + c] = acc[i][j][r];
    }
}

// ---------------- kernel 4: rmsnorm + rope(table) + gain, split qkv head-major bf16 ---
__global__ __launch_bounds__(128) void postproc(
    const float* __restrict__ qkv, const float* __restrict__ qgain,
    const float* __restrict__ rt,
    u16* __restrict__ qb, u16* __restrict__ kb, u16* __restrict__ vb)
{
  int idx = blockIdx.x;
  int slot = idx % 24;
  int m = idx / 24;
  int b = m / Tc, t = m % Tc;
  int d = threadIdx.x;
  if (slot >= 20) { // v: plain cast
    int kvh = slot - 20;
    float val = qkv[m * NQKVc + 2560 + kvh*HDc + d];
    vb[((b*NKVc + kvh)*Tc + t)*HDc + d] = f2bf(val);
    return;
  }
  __shared__ float xn[HDc];
  __shared__ float red[2];
  bool isq = slot < 16;
  int col = isq ? slot*HDc + d : DIMc + (slot-16)*HDc + d;
  float val = qkv[m * NQKVc + col];
  float ss = val * val;
  #pragma unroll
  for (int mk = 1; mk < 64; mk <<= 1) ss += __shfl_xor(ss, mk);
  if ((d & 63) == 0) red[d >> 6] = ss;
  __syncthreads();
  float tot = red[0] + red[1];
  float rn = rsqrtf(tot * (1.0f/HDc) + 1.1920928955078125e-07f);
  xn[d] = val * rn;
  __syncthreads();
  int j = d & 63;
  float2 cs = *(const float2*)(rt + (t*64 + j)*2);
  float x1 = xn[j], x2 = xn[j + 64];
  float out = (d < 64) ? (x1*cs.x + x2*cs.y) : (-x1*cs.y + x2*cs.x);
  if (isq) {
    out *= qgain[slot];
    qb[((b*NHc + slot)*Tc + t)*HDc + d] = f2bf(out);
  } else {
    kb[((b*NKVc + (slot-16))*Tc + t)*HDc + d] = f2bf(out);
  }
}

// ---------------- kernel 4b: V transpose to [d][t] with padded stride ----------------
__global__ __launch_bounds__(256) void transpose_v(
    const u16* __restrict__ vbi, u16* __restrict__ vtb)
{
  __shared__ u16 tile[64][72];
  int t0 = blockIdx.x * 64, d0 = blockIdx.y * 64, s = blockIdx.z;
  const u16* src = vbi + (size_t)s * Tc * HDc;
  u16* dst = vtb + (size_t)s * HDc * TPc;
  int tr = threadIdx.x >> 3;       // 0..31
  int c8 = (threadIdx.x & 7) * 8;  // 0..56
  #pragma unroll
  for (int i = 0; i < 2; i++) {
    int t = i*32 + tr;
    *(bf16x8*)&tile[t][c8] = *(const bf16x8*)(src + (size_t)(t0 + t)*HDc + d0 + c8);
  }
  __syncthreads();
  #pragma unroll
  for (int i = 0; i < 2; i++) {
    int d = i*32 + tr;
    u16 o[8];
    #pragma unroll
    for (int j = 0; j < 8; j++) o[j] = tile[c8 + j][d];
    *(u16x4*)(dst + (size_t)(d0 + d)*TPc + t0 + c8)     = (u16x4){o[0],o[1],o[2],o[3]};
    *(u16x4*)(dst + (size_t)(d0 + d)*TPc + t0 + c8 + 4) = (u16x4){o[4],o[5],o[6],o[7]};
  }
}

// ---------------- kernel 5: flash attention, pair-balanced causal, static-max softmax -
// grid (16, B*NH); block 256 = 4 waves. Block p handles q-tiles {31-p (frag0), p (frag1)}
// interleaved in one KV sweep. Softmax uses NO running max (|s*scale| <= 11.4*gain, safe
// in fp32 up to gain~7) -> no cross-lane shuffles and no O-rescale inside the KV loop.
__global__ __launch_bounds__(256, 2) void attn(
    const u16* __restrict__ qb, const u16* __restrict__ kb,
    const u16* __restrict__ vtb, const u16* __restrict__ vb,
    u16* __restrict__ yb)
{
  __shared__ float Ps[4][2][16*68];   // per-wave, per-frag P round-trip (fp32, padded)

  const int tid = threadIdx.x, wave = tid >> 6, lane = tid & 63;
  const int p = blockIdx.x;            // pair index 0..15
  const int bh = blockIdx.y;
  const int b = bh >> 4, h = bh & 15;
  const int kvh = h >> 2;
  const int fr = lane & 15, quad = lane >> 4;

  const int qt0 = 31 - p, qt1 = p;
  const int qw0 = qt0*64 + wave*16, qw1 = qt1*64 + wave*16;

  const u16* Qb = qb + (size_t)(b*NHc + h)*Tc*HDc;
  const u16* Kp = kb + (size_t)(b*NKVc + kvh)*Tc*HDc;
  const u16* Vp = vb + (size_t)(b*NKVc + kvh)*Tc*HDc;
  const u16* Vt = vtb + (size_t)(b*NKVc + kvh)*HDc*TPc;

  bf16x8 qf[2][4];
  #pragma unroll
  for (int c = 0; c < 4; c++) {
    qf[0][c] = *(const bf16x8*)(Qb + (size_t)(qw0 + fr)*HDc + c*32 + quad*8);
    qf[1][c] = *(const bf16x8*)(Qb + (size_t)(qw1 + fr)*HDc + c*32 + quad*8);
  }

  f32x4 Oc[2][8];
  float l_part[2][4];                  // per-LANE partial row sums (no per-iter reduce)
  #pragma unroll
  for (int f = 0; f < 2; f++) {
    #pragma unroll
    for (int oc = 0; oc < 8; oc++) Oc[f][oc] = (f32x4){0.f,0.f,0.f,0.f};
    #pragma unroll
    for (int r = 0; r < 4; r++) l_part[f][r] = 0.f;
  }

  const float sLOG = 0.08838834764831845f * 1.4426950408889634f; // scale * log2(e)
  const int ntiles = 32 - p;

  for (int it = 0; it < ntiles; it++) {
    const int kv0 = it * 64;
    const bool act1 = (it <= p);
    // S = Q K^T for both fragments, shared K loads
    f32x4 s[2][4];
    #pragma unroll
    for (int cc = 0; cc < 4; cc++) { s[0][cc] = (f32x4){0.f,0.f,0.f,0.f}; s[1][cc] = (f32x4){0.f,0.f,0.f,0.f}; }
    #pragma unroll
    for (int cc = 0; cc < 4; cc++) {
      const u16* kp = Kp + (size_t)(kv0 + cc*16 + fr)*HDc + quad*8;
      bf16x8 kf0 = *(const bf16x8*)(kp);
      bf16x8 kf1 = *(const bf16x8*)(kp + 32);
      bf16x8 kf2 = *(const bf16x8*)(kp + 64);
      bf16x8 kf3 = *(const bf16x8*)(kp + 96);
      s[0][cc] = __builtin_amdgcn_mfma_f32_16x16x32_bf16(qf[0][0], kf0, s[0][cc], 0, 0, 0);
      s[0][cc] = __builtin_amdgcn_mfma_f32_16x16x32_bf16(qf[0][1], kf1, s[0][cc], 0, 0, 0);
      s[0][cc] = __builtin_amdgcn_mfma_f32_16x16x32_bf16(qf[0][2], kf2, s[0][cc], 0, 0, 0);
      s[0][cc] = __builtin_amdgcn_mfma_f32_16x16x32_bf16(qf[0][3], kf3, s[0][cc], 0, 0, 0);
      if (act1) {
        s[1][cc] = __builtin_amdgcn_mfma_f32_16x16x32_bf16(qf[1][0], kf0, s[1][cc], 0, 0, 0);
        s[1][cc] = __builtin_amdgcn_mfma_f32_16x16x32_bf16(qf[1][1], kf1, s[1][cc], 0, 0, 0);
        s[1][cc] = __builtin_amdgcn_mfma_f32_16x16x32_bf16(qf[1][2], kf2, s[1][cc], 0, 0, 0);
        s[1][cc] = __builtin_amdgcn_mfma_f32_16x16x32_bf16(qf[1][3], kf3, s[1][cc], 0, 0, 0);
      }
    }
    // exponentiate (shift-free softmax numerator) + per-lane l accumulation
    #pragma unroll
    for (int f = 0; f < 2; f++) {
      if (f == 0 || act1) {
        const int qtf = (f == 0) ? qt0 : qt1;
        const int qwf = (f == 0) ? qw0 : qw1;
        const bool diag = (it == qtf);
        #pragma unroll
        for (int r = 0; r < 4; r++) {
          int qrow = qwf + quad*4 + r;
          #pragma unroll
          for (int cc = 0; cc < 4; cc++) {
            float arg = s[f][cc][r] * sLOG;
            if (diag && (kv0 + cc*16 + fr > qrow)) arg = -1e30f;
            float e = exp2f(arg);
            l_part[f][r] += e;
            Ps[wave][f][(quad*4 + r)*68 + cc*16 + fr] = e;
          }
        }
      }
    }
    asm volatile("s_waitcnt lgkmcnt(0)" ::: "memory");
    bf16x8 pf[2][2];
    #pragma unroll
    for (int f = 0; f < 2; f++) {
      if (f == 0 || act1) {
        #pragma unroll
        for (int kc = 0; kc < 2; kc++) {
          f32x4 a  = *(const f32x4*)&Ps[wave][f][fr*68 + kc*32 + quad*8];
          f32x4 b2 = *(const f32x4*)&Ps[wave][f][fr*68 + kc*32 + quad*8 + 4];
          pf[f][kc] = (bf16x8){(short)f2bf(a[0]), (short)f2bf(a[1]), (short)f2bf(a[2]), (short)f2bf(a[3]),
                               (short)f2bf(b2[0]), (short)f2bf(b2[1]), (short)f2bf(b2[2]), (short)f2bf(b2[3])};
        }
      }
    }
    // O += P V  (shared V^T loads)
    #pragma unroll
    for (int oc = 0; oc < 8; oc++) {
      const u16* vp = Vt + (size_t)(oc*16 + fr)*TPc + kv0 + quad*8;
      bf16x8 vf0 = *(const bf16x8*)(vp);
      bf16x8 vf1 = *(const bf16x8*)(vp + 32);
      Oc[0][oc] = __builtin_amdgcn_mfma_f32_16x16x32_bf16(pf[0][0], vf0, Oc[0][oc], 0, 0, 0);
      Oc[0][oc] = __builtin_amdgcn_mfma_f32_16x16x32_bf16(pf[0][1], vf1, Oc[0][oc], 0, 0, 0);
      if (act1) {
        Oc[1][oc] = __builtin_amdgcn_mfma_f32_16x16x32_bf16(pf[1][0], vf0, Oc[1][oc], 0, 0, 0);
        Oc[1][oc] = __builtin_amdgcn_mfma_f32_16x16x32_bf16(pf[1][1], vf1, Oc[1][oc], 0, 0, 0);
      }
    }
  }

  // epilogue both fragments: reduce l across lanes, normalize, remove v-projection
  #pragma unroll
  for (int f = 0; f < 2; f++) {
    const int qwf = (f == 0) ? qw0 : qw1;
    #pragma unroll
    for (int r = 0; r < 4; r++) {
      int qrow = qwf + quad*4 + r;
      float l = l_part[f][r];
      l += __shfl_xor(l, 1); l += __shfl_xor(l, 2);
      l += __shfl_xor(l, 4); l += __shfl_xor(l, 8);
      float linv = 1.0f / l;
      float vv[8], dot = 0.f, n2 = 0.f;
      #pragma unroll
      for (int oc = 0; oc < 8; oc++) {
        float y = Oc[f][oc][r] * linv;
        Oc[f][oc][r] = y;
        float v = bf2f(Vp[(size_t)qrow*HDc + oc*16 + fr]);
        vv[oc] = v; dot += y * v; n2 += v * v;
      }
      dot += __shfl_xor(dot, 1); dot += __shfl_xor(dot, 2);
      dot += __shfl_xor(dot, 4); dot += __shfl_xor(dot, 8);
      n2  += __shfl_xor(n2, 1);  n2  += __shfl_xor(n2, 2);
      n2  += __shfl_xor(n2, 4);  n2  += __shfl_xor(n2, 8);
      float nn = fmaxf(sqrtf(n2), 1e-12f);
      float coef = dot / (nn * nn);
      u16* yrow = yb + ((size_t)(b*Tc) + qrow)*DIMc + h*HDc;
      #pragma unroll
      for (int oc = 0; oc < 8; oc++)
        yrow[oc*16 + fr] = f2bf(Oc[f][oc][r] - coef * vv[oc]);
    }
  }
}

// ---------------- launcher ----------------
extern "C" void kernel_launch(void* const* d_in, const int* in_sizes, int n_in,
                              void* d_out, int out_size, void* d_ws, size_t ws_size,
                              hipStream_t stream) {
  const float* x  = (const float*)d_in[0];
  const float* sf = (const float*)d_in[1];
  const float* wq = (const float*)d_in[2];
  const float* wk = (const float*)d_in[3];
  const float* wv = (const float*)d_in[4];
  const float* wp = (const float*)d_in[5];
  const float* qg = (const float*)d_in[6];
  float* out = (float*)d_out;

  char* p = (char*)d_ws;
  u16* Wqkv  = (u16*)p; p += (size_t)NQKVc * DIMc * 2;
  u16* Wproj = (u16*)p; p += (size_t)DIMc * DIMc * 2;
  u16* xb    = (u16*)p; p += (size_t)Mc * DIMc * 2;
  float* qkvb = (float*)p; p += (size_t)Mc * NQKVc * 4;
  u16* qbuf  = (u16*)p; p += (size_t)Bc * NHc * Tc * HDc * 2;
  u16* kbuf  = (u16*)p; p += (size_t)Bc * NKVc * Tc * HDc * 2;
  u16* vbuf  = (u16*)p; p += (size_t)Bc * NKVc * Tc * HDc * 2;
  u16* vtbuf = (u16*)p; p += (size_t)Bc * NKVc * HDc * TPc * 2;
  float* rtab = (float*)p; p += (size_t)Tc * 64 * 2 * 4;
  u16* ybuf  = xb; // xb dead after QKV GEMM

  prep_weights<<<5120, 256, 0, stream>>>(wq, wk, wv, wp, sf, Wqkv, Wproj);
  cast_x<<<(Mc * DIMc) / (256 * 4), 256, 0, stream>>>(x, xb);
  rope_table<<<(Tc * 64) / 256, 256, 0, stream>>>(rtab);
  gemm_nt<<<dim3(Mc/128, NQKVc/128), 256, 0, stream>>>(xb, Wqkv, qkvb, Mc, NQKVc, DIMc);
  postproc<<<Mc * 24, 128, 0, stream>>>(qkvb, qg, rtab, qbuf, kbuf, vbuf);
  transpose_v<<<dim3(Tc/64, HDc/64, Bc*NKVc), 256, 0, stream>>>(vbuf, vtbuf);
  attn<<<dim3(16, Bc*NHc), 256, 0, stream>>>(qbuf, kbuf, vtbuf, vbuf, ybuf);
  gemm_nt<<<dim3(Mc/128, DIMc/128), 256, 0, stream>>>(ybuf, Wproj, out, Mc, DIMc, DIMc);
}